// Round 2
// baseline (329.881 us; speedup 1.0000x reference)
//
#include <hip/hip_runtime.h>

// LocallyConnected2D: out[b,p,f] = sum_k x_patch[b,p,k] * kernel[p,k,f] + bias[p,f]
// B=16, H=W=64, C=32, KH=KW=3, OH=OW=62, P=3844, K=288, F=64, all fp32.
//
// Memory-bound on the 283 MB weight stream (read exactly once: all 16
// batches accumulate in registers). R1 change: 1 output feature per thread
// (was 4) -> 4x the waves (3844, ~3.75/SIMD) for latency hiding. Weight
// loads are 4B/lane but a wave's 64 lanes cover one contiguous 256B row.
// One p per wave -> x addresses are wave-uniform (readfirstlane'd) ->
// scalar/broadcast loads that hit L2 (x is only 8 MB).

namespace {
constexpr int Hc = 64, Wc = 64, Cc = 32;
constexpr int OWc = 62;
constexpr int Pc = 62 * 62;   // 3844
constexpr int Fc = 64;
constexpr int Kc = 288;
constexpr int BDIM = 16;
constexpr int PPB = 2;        // p's per block (one per wave)
}

__global__ __launch_bounds__(128, 4)
void lc2d(const float* __restrict__ x, const float* __restrict__ kern,
          const float* __restrict__ bias, float* __restrict__ out)
{
    const int t = threadIdx.x;
    const int f = t & 63;                                   // lane = feature
    const int psub = __builtin_amdgcn_readfirstlane(t) >> 6; // wave id, SGPR
    const int p = blockIdx.x * PPB + psub;
    const int oh = p / OWc;
    const int ow = p - oh * OWc;

    const float* kcol = kern + (size_t)p * (Kc * Fc) + f;

    float acc[BDIM];
    const float bv = bias[(size_t)p * Fc + f];
    #pragma unroll
    for (int b = 0; b < BDIM; ++b) acc[b] = bv;

    #pragma unroll
    for (int kh = 0; kh < 3; ++kh) {
      #pragma unroll
      for (int kw = 0; kw < 3; ++kw) {
        // x[b, oh+kh, ow+kw, c] — wave-uniform base
        const float* xb = x + ((size_t)(oh + kh) * Wc + (ow + kw)) * Cc;
        // kernel[p, k, f], k = kh*96 + kw*32 + c
        const float* kk = kcol + (size_t)(kh * 96 + kw * 32) * Fc;
        #pragma unroll 2
        for (int c4 = 0; c4 < 8; ++c4) {
          const float kv0 = kk[(c4 * 4 + 0) * Fc];
          const float kv1 = kk[(c4 * 4 + 1) * Fc];
          const float kv2 = kk[(c4 * 4 + 2) * Fc];
          const float kv3 = kk[(c4 * 4 + 3) * Fc];
          #pragma unroll
          for (int b = 0; b < BDIM; ++b) {
            const float4 xv = *(const float4*)(xb + (size_t)b * (Hc * Wc * Cc) + c4 * 4);
            acc[b] = fmaf(xv.x, kv0, fmaf(xv.y, kv1, fmaf(xv.z, kv2, fmaf(xv.w, kv3, acc[b]))));
          }
        }
      }
    }

    // out[b, p, f]
    #pragma unroll
    for (int b = 0; b < BDIM; ++b)
      out[((size_t)b * Pc + p) * Fc + f] = acc[b];
}

extern "C" void kernel_launch(void* const* d_in, const int* in_sizes, int n_in,
                              void* d_out, int out_size, void* d_ws, size_t ws_size,
                              hipStream_t stream)
{
    const float* x    = (const float*)d_in[0];
    const float* kern = (const float*)d_in[1];
    const float* bias = (const float*)d_in[2];
    float* out = (float*)d_out;
    dim3 grid(Pc / PPB);   // 3844/2 = 1922 blocks
    lc2d<<<grid, 128, 0, stream>>>(x, kern, bias, out);
}